// Round 9
// baseline (5157.126 us; speedup 1.0000x reference)
//
#include <hip/hip_runtime.h>

#define DH 30
#define SLOPE 0.01f

typedef float v2 __attribute__((ext_vector_type(2)));

// Launder a wave-uniform pointer through ds_bpermute (__shfl) so divergence
// analysis marks it divergent: weight reads then use the VECTOR memory path
// (global_load + counted vmcnt waits, pipelineable) instead of s_load
// (SMEM completes out-of-order -> lgkmcnt(0) full drain before every use).
// All lanes read the same address -> single L1 transaction, broadcast.
__device__ __forceinline__ const float* vptr(const float* p) {
    unsigned long long a = (unsigned long long)p;
    int lo = __shfl((int)(unsigned)(a & 0xffffffffull), 0);
    int hi = __shfl((int)(unsigned)(a >> 32), 0);
    return (const float*)((((unsigned long long)(unsigned)hi) << 32) |
                          (unsigned long long)(unsigned)lo);
}

__global__ __launch_bounds__(256) void mlp_fwdbwd(
    const float4* __restrict__ pe,
    const float*  __restrict__ q,
    const float4* __restrict__ s,
    const float* __restrict__ W1g, const float* __restrict__ b1g,
    const float* __restrict__ W2g, const float* __restrict__ b2g,
    const float* __restrict__ W3g, const float* __restrict__ b3g,
    const float* __restrict__ W4g, const float* __restrict__ b4g,
    float* __restrict__ dout, int n)
{
    const int i = blockIdx.x * 256 + threadIdx.x;
    if (i >= n) return;

    const float* W1 = vptr(W1g);
    const float* b1 = vptr(b1g);
    const float* W2 = vptr(W2g);
    const float* b2 = vptr(b2g);
    const float* W3 = vptr(W3g);
    const float* b3 = vptr(b3g);
    const float* W4 = vptr(W4g);
    const float* b4 = vptr(b4g);

    const float4 vpe = pe[i];
    const float4 vs  = s[i];
    const float  vq  = q[i];
    float x[9] = { vpe.x, vpe.y, vpe.z, vpe.w, vq, vs.x, vs.y, vs.z, vs.w };

    v2 acc[15];
    v2 hh[15];
    unsigned m1 = 0, m2 = 0, m3 = 0;

    // ---- layer 1: (x @ W1) then + b1 (acc from 0, k ascending, fma) ----
    #pragma unroll
    for (int jj = 0; jj < 15; ++jj) acc[jj] = (v2){0.f, 0.f};
    #pragma unroll
    for (int k = 0; k < 9; ++k) {
        const v2 xv = { x[k], x[k] };
        const v2* Wr = reinterpret_cast<const v2*>(W1 + k * DH);
        #pragma unroll
        for (int jj = 0; jj < 15; ++jj)
            acc[jj] = __builtin_elementwise_fma(xv, Wr[jj], acc[jj]);
    }
    {
        const v2* bv = reinterpret_cast<const v2*>(b1);
        #pragma unroll
        for (int jj = 0; jj < 15; ++jj) {
            const v2 z = acc[jj] + bv[jj];
            if (z.x > 0.f) m1 |= (1u << (2*jj));
            if (z.y > 0.f) m1 |= (1u << (2*jj+1));
            hh[jj].x = (z.x > 0.f) ? z.x : SLOPE * z.x;
            hh[jj].y = (z.y > 0.f) ? z.y : SLOPE * z.y;
        }
    }

    // ---- layer 2 ----
    #pragma unroll
    for (int jj = 0; jj < 15; ++jj) acc[jj] = (v2){0.f, 0.f};
    #pragma unroll
    for (int k = 0; k < DH; ++k) {
        const float hk = hh[k >> 1][k & 1];
        const v2 hv = { hk, hk };
        const v2* Wr = reinterpret_cast<const v2*>(W2 + k * DH);
        #pragma unroll
        for (int jj = 0; jj < 15; ++jj)
            acc[jj] = __builtin_elementwise_fma(hv, Wr[jj], acc[jj]);
    }
    {
        const v2* bv = reinterpret_cast<const v2*>(b2);
        #pragma unroll
        for (int jj = 0; jj < 15; ++jj) {
            const v2 z = acc[jj] + bv[jj];
            if (z.x > 0.f) m2 |= (1u << (2*jj));
            if (z.y > 0.f) m2 |= (1u << (2*jj+1));
            hh[jj].x = (z.x > 0.f) ? z.x : SLOPE * z.x;
            hh[jj].y = (z.y > 0.f) ? z.y : SLOPE * z.y;
        }
    }

    // ---- layer 3 ----
    #pragma unroll
    for (int jj = 0; jj < 15; ++jj) acc[jj] = (v2){0.f, 0.f};
    #pragma unroll
    for (int k = 0; k < DH; ++k) {
        const float hk = hh[k >> 1][k & 1];
        const v2 hv = { hk, hk };
        const v2* Wr = reinterpret_cast<const v2*>(W3 + k * DH);
        #pragma unroll
        for (int jj = 0; jj < 15; ++jj)
            acc[jj] = __builtin_elementwise_fma(hv, Wr[jj], acc[jj]);
    }
    // output dot: scalar, j ascending (bit-identical to passing R6/R8 kernels)
    float outv = 0.f;
    #pragma unroll
    for (int j = 0; j < DH; ++j) {
        const float z = acc[j >> 1][j & 1] + b3[j];
        if (z > 0.f) m3 |= (1u << j);
        const float hz = (z > 0.f) ? z : SLOPE * z;
        outv = fmaf(hz, W4[j], outv);
    }
    outv += b4[0];

    // ---- backward (mask-driven; value-continuous, packed dots) ----
    v2 g3[15];
    {
        const v2* w4v = reinterpret_cast<const v2*>(W4);
        #pragma unroll
        for (int jj = 0; jj < 15; ++jj) {
            const v2 w = w4v[jj];
            g3[jj].x = ((m3 >> (2*jj))   & 1u) ? w.x : SLOPE * w.x;
            g3[jj].y = ((m3 >> (2*jj+1)) & 1u) ? w.y : SLOPE * w.y;
        }
    }
    v2 g2[15];
    #pragma unroll
    for (int k = 0; k < DH; ++k) {
        v2 d = (v2){0.f, 0.f};
        const v2* Wr = reinterpret_cast<const v2*>(W3 + k * DH);
        #pragma unroll
        for (int jj = 0; jj < 15; ++jj)
            d = __builtin_elementwise_fma(g3[jj], Wr[jj], d);
        const float dot = d.x + d.y;
        g2[k >> 1][k & 1] = ((m2 >> k) & 1u) ? dot : SLOPE * dot;
    }
    v2 g1[15];
    #pragma unroll
    for (int k = 0; k < DH; ++k) {
        v2 d = (v2){0.f, 0.f};
        const v2* Wr = reinterpret_cast<const v2*>(W2 + k * DH);
        #pragma unroll
        for (int jj = 0; jj < 15; ++jj)
            d = __builtin_elementwise_fma(g2[jj], Wr[jj], d);
        const float dot = d.x + d.y;
        g1[k >> 1][k & 1] = ((m1 >> k) & 1u) ? dot : SLOPE * dot;
    }
    float gx[9];
    #pragma unroll
    for (int k = 0; k < 9; ++k) {
        v2 d = (v2){0.f, 0.f};
        const v2* Wr = reinterpret_cast<const v2*>(W1 + k * DH);
        #pragma unroll
        for (int jj = 0; jj < 15; ++jj)
            d = __builtin_elementwise_fma(g1[jj], Wr[jj], d);
        gx[k] = d.x + d.y;
    }

    // ---- stores: [out(N) | h_s(4N) | h_q(N) | h_pe(4N)] ----
    dout[i] = outv;
    float4* hs = reinterpret_cast<float4*>(dout + (size_t)n);
    hs[i] = make_float4(gx[5], gx[6], gx[7], gx[8]);
    dout[(size_t)5 * n + i] = gx[4];
    float4* hpe = reinterpret_cast<float4*>(dout + (size_t)6 * n);
    hpe[i] = make_float4(gx[0], gx[1], gx[2], gx[3]);
}

extern "C" void kernel_launch(void* const* d_in, const int* in_sizes, int n_in,
                              void* d_out, int out_size, void* d_ws, size_t ws_size,
                              hipStream_t stream) {
    const int n = in_sizes[1];  // input_q has N elements
    const int blocks = (n + 255) / 256;
    hipLaunchKernelGGL(mlp_fwdbwd, dim3(blocks), dim3(256), 0, stream,
        (const float4*)d_in[0], (const float*)d_in[1], (const float4*)d_in[2],
        (const float*)d_in[3], (const float*)d_in[4],
        (const float*)d_in[5], (const float*)d_in[6],
        (const float*)d_in[7], (const float*)d_in[8],
        (const float*)d_in[9], (const float*)d_in[10],
        (float*)d_out, n);
}

// Round 10
// 237.362 us; speedup vs baseline: 21.7268x; 21.7268x over previous
//
#include <hip/hip_runtime.h>

#define DH 30
#define SLOPE 0.01f

typedef float v2 __attribute__((ext_vector_type(2)));

// Weights via scalar pipe (wave-uniform, compile-time offsets -> s_load ->
// SGPR pair -> v_pk_fma_f32 with SGPR-pair operand). R9 proved weights must
// stay in SGPRs: LDS/VMEM paths put weight values in VGPRs -> regalloc
// explosion + spills. min-waves=7 caps VGPR ~73 (live set ~70) for +1
// resident wave/SIMD of s_load-latency hiding.
__global__ __launch_bounds__(256, 7) void mlp_fwdbwd(
    const float4* __restrict__ pe,
    const float*  __restrict__ q,
    const float4* __restrict__ s,
    const float* __restrict__ W1, const float* __restrict__ b1,
    const float* __restrict__ W2, const float* __restrict__ b2,
    const float* __restrict__ W3, const float* __restrict__ b3,
    const float* __restrict__ W4, const float* __restrict__ b4,
    float* __restrict__ dout, int n)
{
    const int i = blockIdx.x * 256 + threadIdx.x;
    if (i >= n) return;

    const float4 vpe = pe[i];
    const float4 vs  = s[i];
    const float  vq  = q[i];
    float x[9] = { vpe.x, vpe.y, vpe.z, vpe.w, vq, vs.x, vs.y, vs.z, vs.w };

    v2 acc[15];
    v2 hh[15];
    unsigned m1 = 0, m2 = 0, m3 = 0;
    const v2 slope2 = { SLOPE, SLOPE };

    // ---- layer 1: (x @ W1) then + b1 (acc from 0, k ascending, fma) ----
    #pragma unroll
    for (int jj = 0; jj < 15; ++jj) acc[jj] = (v2){0.f, 0.f};
    #pragma unroll
    for (int k = 0; k < 9; ++k) {
        const v2 xv = { x[k], x[k] };
        const v2* Wr = reinterpret_cast<const v2*>(W1 + k * DH);
        #pragma unroll
        for (int jj = 0; jj < 15; ++jj)
            acc[jj] = __builtin_elementwise_fma(xv, Wr[jj], acc[jj]);
    }
    {
        const v2* bv = reinterpret_cast<const v2*>(b1);
        #pragma unroll
        for (int jj = 0; jj < 15; ++jj) {
            const v2 z = acc[jj] + bv[jj];
            if (z.x > 0.f) m1 |= (1u << (2*jj));
            if (z.y > 0.f) m1 |= (1u << (2*jj+1));
            // bit-identical to (z>0?z:0.01*z): max picks z exactly when z>0,
            // else the identically-rounded product 0.01*z
            hh[jj] = __builtin_elementwise_max(z, z * slope2);
        }
    }

    // ---- layer 2 ----
    #pragma unroll
    for (int jj = 0; jj < 15; ++jj) acc[jj] = (v2){0.f, 0.f};
    #pragma unroll
    for (int k = 0; k < DH; ++k) {
        const float hk = hh[k >> 1][k & 1];
        const v2 hv = { hk, hk };
        const v2* Wr = reinterpret_cast<const v2*>(W2 + k * DH);
        #pragma unroll
        for (int jj = 0; jj < 15; ++jj)
            acc[jj] = __builtin_elementwise_fma(hv, Wr[jj], acc[jj]);
    }
    {
        const v2* bv = reinterpret_cast<const v2*>(b2);
        #pragma unroll
        for (int jj = 0; jj < 15; ++jj) {
            const v2 z = acc[jj] + bv[jj];
            if (z.x > 0.f) m2 |= (1u << (2*jj));
            if (z.y > 0.f) m2 |= (1u << (2*jj+1));
            hh[jj] = __builtin_elementwise_max(z, z * slope2);
        }
    }

    // ---- layer 3 ----
    #pragma unroll
    for (int jj = 0; jj < 15; ++jj) acc[jj] = (v2){0.f, 0.f};
    #pragma unroll
    for (int k = 0; k < DH; ++k) {
        const float hk = hh[k >> 1][k & 1];
        const v2 hv = { hk, hk };
        const v2* Wr = reinterpret_cast<const v2*>(W3 + k * DH);
        #pragma unroll
        for (int jj = 0; jj < 15; ++jj)
            acc[jj] = __builtin_elementwise_fma(hv, Wr[jj], acc[jj]);
    }
    // output dot: scalar, j ascending (bit-identical to passing R6/R8 kernels)
    float outv = 0.f;
    #pragma unroll
    for (int j = 0; j < DH; ++j) {
        const float z = acc[j >> 1][j & 1] + b3[j];
        if (z > 0.f) m3 |= (1u << j);
        const float hz = (z > 0.f) ? z : SLOPE * z;
        outv = fmaf(hz, W4[j], outv);
    }
    outv += b4[0];

    // ---- backward (mask-driven; value-continuous, packed dots) ----
    v2 g3[15];
    {
        const v2* w4v = reinterpret_cast<const v2*>(W4);
        #pragma unroll
        for (int jj = 0; jj < 15; ++jj) {
            const v2 w = w4v[jj];
            g3[jj].x = ((m3 >> (2*jj))   & 1u) ? w.x : SLOPE * w.x;
            g3[jj].y = ((m3 >> (2*jj+1)) & 1u) ? w.y : SLOPE * w.y;
        }
    }
    v2 g2[15];
    #pragma unroll
    for (int k = 0; k < DH; ++k) {
        v2 d = (v2){0.f, 0.f};
        const v2* Wr = reinterpret_cast<const v2*>(W3 + k * DH);
        #pragma unroll
        for (int jj = 0; jj < 15; ++jj)
            d = __builtin_elementwise_fma(g3[jj], Wr[jj], d);
        const float dot = d.x + d.y;
        g2[k >> 1][k & 1] = ((m2 >> k) & 1u) ? dot : SLOPE * dot;
    }
    v2 g1[15];
    #pragma unroll
    for (int k = 0; k < DH; ++k) {
        v2 d = (v2){0.f, 0.f};
        const v2* Wr = reinterpret_cast<const v2*>(W2 + k * DH);
        #pragma unroll
        for (int jj = 0; jj < 15; ++jj)
            d = __builtin_elementwise_fma(g2[jj], Wr[jj], d);
        const float dot = d.x + d.y;
        g1[k >> 1][k & 1] = ((m1 >> k) & 1u) ? dot : SLOPE * dot;
    }
    float gx[9];
    #pragma unroll
    for (int k = 0; k < 9; ++k) {
        v2 d = (v2){0.f, 0.f};
        const v2* Wr = reinterpret_cast<const v2*>(W1 + k * DH);
        #pragma unroll
        for (int jj = 0; jj < 15; ++jj)
            d = __builtin_elementwise_fma(g1[jj], Wr[jj], d);
        gx[k] = d.x + d.y;
    }

    // ---- stores: [out(N) | h_s(4N) | h_q(N) | h_pe(4N)] ----
    dout[i] = outv;
    float4* hs = reinterpret_cast<float4*>(dout + (size_t)n);
    hs[i] = make_float4(gx[5], gx[6], gx[7], gx[8]);
    dout[(size_t)5 * n + i] = gx[4];
    float4* hpe = reinterpret_cast<float4*>(dout + (size_t)6 * n);
    hpe[i] = make_float4(gx[0], gx[1], gx[2], gx[3]);
}

extern "C" void kernel_launch(void* const* d_in, const int* in_sizes, int n_in,
                              void* d_out, int out_size, void* d_ws, size_t ws_size,
                              hipStream_t stream) {
    const int n = in_sizes[1];  // input_q has N elements
    const int blocks = (n + 255) / 256;
    hipLaunchKernelGGL(mlp_fwdbwd, dim3(blocks), dim3(256), 0, stream,
        (const float4*)d_in[0], (const float*)d_in[1], (const float4*)d_in[2],
        (const float*)d_in[3], (const float*)d_in[4],
        (const float*)d_in[5], (const float*)d_in[6],
        (const float*)d_in[7], (const float*)d_in[8],
        (const float*)d_in[9], (const float*)d_in[10],
        (float*)d_out, n);
}